// Round 3
// baseline (1867.868 us; speedup 1.0000x reference)
//
#include <hip/hip_runtime.h>

#define F 64      // F_IN == HID
#define EF 32
#define COUT 4

typedef unsigned int uint;
typedef unsigned short ushort;

__device__ inline ushort f2bf(float f) {           // RNE float->bf16
    uint u = __float_as_uint(f);
    return (ushort)((u + 0x7fff + ((u >> 16) & 1)) >> 16);
}
__device__ inline float bf2f(ushort u) {
    return __uint_as_float(((uint)u) << 16);
}

// ---------------------------------------------------------------- kernels

__global__ void k_deg(const int* __restrict__ dst, int* __restrict__ deg, int E) {
    int i = blockIdx.x * blockDim.x + threadIdx.x;
    if (i < E) atomicAdd(&deg[dst[i]], 1);
}

__global__ void k_dinv(const int* __restrict__ deg, float* __restrict__ dinv, int n) {
    int i = blockIdx.x * blockDim.x + threadIdx.x;
    if (i < n) dinv[i] = rsqrtf((float)(deg[i] + 1));
}

__global__ void k_xcast(const float* __restrict__ x, ushort* __restrict__ xb, int n4) {
    int i = blockIdx.x * 256 + threadIdx.x;
    if (i >= n4) return;
    float4 v = *(const float4*)(x + (size_t)i * 4);
    ushort4 o;
    o.x = f2bf(v.x); o.y = f2bf(v.y); o.z = f2bf(v.z); o.w = f2bf(v.w);
    *(ushort4*)(xb + (size_t)i * 4) = o;
}

// ---- exclusive scan of deg -> rowptr ----

__global__ void k_blocksum(const int* __restrict__ deg, int* __restrict__ bsum, int n) {
    __shared__ int sm[256];
    int i = blockIdx.x * 256 + threadIdx.x;
    sm[threadIdx.x] = (i < n) ? deg[i] : 0;
    __syncthreads();
    for (int s = 128; s > 0; s >>= 1) {
        if (threadIdx.x < s) sm[threadIdx.x] += sm[threadIdx.x + s];
        __syncthreads();
    }
    if (threadIdx.x == 0) bsum[blockIdx.x] = sm[0];
}

__global__ void k_scanb(const int* __restrict__ bsum, int* __restrict__ boffs, int nb) {
    int lane = threadIdx.x;
    int carry = 0;
    for (int base = 0; base < nb; base += 64) {
        int v = (base + lane < nb) ? bsum[base + lane] : 0;
        int incl = v;
        #pragma unroll
        for (int off = 1; off < 64; off <<= 1) {
            int t = __shfl_up(incl, off);
            if (lane >= off) incl += t;
        }
        if (base + lane < nb) boffs[base + lane] = carry + incl - v;
        carry += __shfl(incl, 63);
    }
}

__global__ void k_rowptr(const int* __restrict__ deg, const int* __restrict__ boffs,
                         int* __restrict__ rowptr, int n) {
    __shared__ int sm[256];
    int tid = threadIdx.x;
    int i = blockIdx.x * 256 + tid;
    int v = (i < n) ? deg[i] : 0;
    sm[tid] = v;
    __syncthreads();
    for (int off = 1; off < 256; off <<= 1) {
        int t = (tid >= off) ? sm[tid - off] : 0;
        __syncthreads();
        sm[tid] += t;
        __syncthreads();
    }
    if (i < n) rowptr[i] = boffs[blockIdx.x] + sm[tid] - v;
}

__global__ void k_bucket(const int* __restrict__ src, const int* __restrict__ dst,
                         const int* __restrict__ rowptr, int* __restrict__ fill,
                         int* __restrict__ es, int E) {
    int e = blockIdx.x * 256 + threadIdx.x;
    if (e >= E) return;
    int d = dst[e];
    int pos = rowptr[d] + atomicAdd(&fill[d], 1);
    es[pos] = src[e];
}

// gather-aggregate: one wave per node, lane = feature (bf16 x rows, f32 accum)
__global__ __launch_bounds__(256) void k_agg(
    const ushort* __restrict__ xb, const float* __restrict__ dinv,
    const int* __restrict__ es, const int* __restrict__ rowptr,
    const int* __restrict__ deg, float* __restrict__ xagg, int n) {
    int node = (blockIdx.x * 256 + threadIdx.x) >> 6;
    int lane = threadIdx.x & 63;
    if (node >= n) return;
    int start = rowptr[node], cnt = deg[node];
    float di = dinv[node];
    float acc = bf2f(xb[(size_t)node * F + lane]) * di * di;
    for (int base = 0; base < cnt; base += 64) {
        int m = min(64, cnt - base);
        int s = 0; float dv = 0.f;
        if (lane < m) { s = es[start + base + lane]; dv = dinv[s]; }
        for (int i = 0; i < m; ++i) {
            int si = __shfl(s, i);
            float wv = __shfl(dv, i) * di;
            acc += bf2f(xb[(size_t)si * F + lane]) * wv;
        }
    }
    xagg[(size_t)node * F + lane] = acc;
}

// M layout: Mz[4096] | Mh[4096] | vz[64] | vh[64]
__global__ void k_weights(const float* __restrict__ Wz, const float* __restrict__ bz,
                          const float* __restrict__ Wh, const float* __restrict__ bh,
                          const float* __restrict__ Wlz, const float* __restrict__ blz,
                          const float* __restrict__ Wlh, const float* __restrict__ blh,
                          float* __restrict__ M) {
    int j = threadIdx.x;
    int k = blockIdx.x;
    if (k < 64) {
        float sz = 0.f, sh = 0.f;
        for (int i = 0; i < 64; ++i) {
            sz += Wz[k * 64 + i] * Wlz[i * 64 + j];
            sh += Wh[k * 64 + i] * Wlh[i * 64 + j];
        }
        M[k * 64 + j]        = sz;
        M[4096 + k * 64 + j] = sh;
    } else {
        float sz = blz[j], sh = blh[j];
        for (int i = 0; i < 64; ++i) {
            sz += bz[i] * Wlz[i * 64 + j];
            sh += bh[i] * Wlh[i * 64 + j];
        }
        M[8192 + j] = sz;
        M[8256 + j] = sh;
    }
}

// Per node: Z=sigmoid(a@Mz+vz); T=tanh(a@Mh+vh); h=(1-Z)T; P=h@W1a+b1; Q=h@W1b (bf16 out)
__global__ __launch_bounds__(512) void k_node(
    const float* __restrict__ xagg, const float* __restrict__ M,
    const float* __restrict__ W1, const float* __restrict__ b1,
    ushort* __restrict__ Pb, ushort* __restrict__ Qb, int n) {
    __shared__ float sm[16384];  // Mz | Mh | W1a | W1b
    for (int i = threadIdx.x; i < 8192; i += 512) sm[i] = M[i];
    for (int i = threadIdx.x; i < 8192; i += 512) sm[8192 + i] = W1[i];
    __syncthreads();
    int wid = threadIdx.x >> 6, lane = threadIdx.x & 63;
    float vz = M[8192 + lane], vh = M[8256 + lane], b1v = b1[lane];
    int wave = blockIdx.x * 8 + wid;
    int nwaves = gridDim.x * 8;
    for (int base = wave * 4; base < n; base += nwaves * 4) {
        float a[4], gz[4], gh[4];
        #pragma unroll
        for (int i = 0; i < 4; ++i) {
            int node = base + i;
            a[i] = (node < n) ? xagg[(size_t)node * F + lane] : 0.f;
            gz[i] = vz; gh[i] = vh;
        }
        #pragma unroll 8
        for (int k = 0; k < 64; ++k) {
            float mz = sm[k * 64 + lane], mh = sm[4096 + k * 64 + lane];
            #pragma unroll
            for (int i = 0; i < 4; ++i) {
                float ak = __shfl(a[i], k);
                gz[i] += ak * mz;
                gh[i] += ak * mh;
            }
        }
        float h[4], p[4], q[4];
        #pragma unroll
        for (int i = 0; i < 4; ++i) {
            float z = 1.f / (1.f + __expf(-gz[i]));
            float t = tanhf(gh[i]);
            h[i] = (1.f - z) * t;
            p[i] = b1v; q[i] = 0.f;
        }
        #pragma unroll 8
        for (int k = 0; k < 64; ++k) {
            float w1a = sm[8192 + k * 64 + lane], w1b = sm[12288 + k * 64 + lane];
            #pragma unroll
            for (int i = 0; i < 4; ++i) {
                float hk = __shfl(h[i], k);
                p[i] += hk * w1a;
                q[i] += hk * w1b;
            }
        }
        #pragma unroll
        for (int i = 0; i < 4; ++i) {
            int node = base + i;
            if (node < n) {
                Pb[(size_t)node * F + lane] = f2bf(p[i]);
                Qb[(size_t)node * F + lane] = f2bf(q[i]);
            }
        }
    }
}

// One edge per LANE; P/Q rows gathered as bf16 (uint4 = 8 elems).
__global__ __launch_bounds__(256) void k_edge(
    const int* __restrict__ src, const int* __restrict__ dst,
    const float* __restrict__ attr,
    const ushort* __restrict__ Pb, const ushort* __restrict__ Qb,
    const float* __restrict__ W1c, const float* __restrict__ W2,
    const float* __restrict__ b2, float* __restrict__ out, int E) {
    int e = blockIdx.x * 256 + threadIdx.x;
    if (e >= E) return;
    int s = src[e], d = dst[e];
    float ar[EF];
    #pragma unroll
    for (int k4 = 0; k4 < EF / 4; ++k4) {
        float4 v = *(const float4*)(attr + (size_t)e * EF + k4 * 4);
        ar[k4 * 4 + 0] = v.x; ar[k4 * 4 + 1] = v.y;
        ar[k4 * 4 + 2] = v.z; ar[k4 * 4 + 3] = v.w;
    }
    const uint4* Ps = (const uint4*)(Pb + (size_t)s * F);
    const uint4* Qd = (const uint4*)(Qb + (size_t)d * F);
    float o0 = b2[0], o1 = b2[1], o2 = b2[2], o3 = b2[3];
    #pragma unroll 2
    for (int j8 = 0; j8 < 8; ++j8) {
        uint4 pv = Ps[j8], qv = Qd[j8];
        uint pu[4] = {pv.x, pv.y, pv.z, pv.w};
        uint qu[4] = {qv.x, qv.y, qv.z, qv.w};
        float pre[8];
        #pragma unroll
        for (int t = 0; t < 4; ++t) {
            pre[2*t]   = __uint_as_float(pu[t] << 16)         + __uint_as_float(qu[t] << 16);
            pre[2*t+1] = __uint_as_float(pu[t] & 0xffff0000u) + __uint_as_float(qu[t] & 0xffff0000u);
        }
        #pragma unroll
        for (int jj = 0; jj < 8; ++jj) {
            int j = j8 * 8 + jj;
            float acc = pre[jj];
            #pragma unroll
            for (int k = 0; k < EF; ++k) acc += ar[k] * W1c[k * 64 + j];
            float h = fmaxf(acc, 0.f);
            o0 += h * W2[j * 4 + 0];
            o1 += h * W2[j * 4 + 1];
            o2 += h * W2[j * 4 + 2];
            o3 += h * W2[j * 4 + 3];
        }
    }
    *(float4*)(out + (size_t)e * 4) = make_float4(o0, o1, o2, o3);
}

// ---------------------------------------------------------------- launch

extern "C" void kernel_launch(void* const* d_in, const int* in_sizes, int n_in,
                              void* d_out, int out_size, void* d_ws, size_t ws_size,
                              hipStream_t stream) {
    const float* x    = (const float*)d_in[0];
    const int*   ei   = (const int*)d_in[1];
    const float* attr = (const float*)d_in[2];
    const float* Wz   = (const float*)d_in[3];
    const float* bz   = (const float*)d_in[4];
    const float* Wh   = (const float*)d_in[7];
    const float* bh   = (const float*)d_in[8];
    const float* Wlz  = (const float*)d_in[9];
    const float* blz  = (const float*)d_in[10];
    const float* Wlh  = (const float*)d_in[13];
    const float* blh  = (const float*)d_in[14];
    const float* W1   = (const float*)d_in[15];
    const float* b1   = (const float*)d_in[16];
    const float* W2   = (const float*)d_in[17];
    const float* b2   = (const float*)d_in[18];
    float* out = (float*)d_out;

    const int N = in_sizes[0] / F;
    const int E = in_sizes[1] / 2;
    const int* src = ei;
    const int* dst = ei + E;
    const int NB = (N + 255) / 256;

    // workspace layout (time-disjoint aliasing):
    //   xagg  : N*F f32                          (k_agg out -> k_node in)
    //   regB  : N*F ushort — xb (xcast->agg), then Qb (node->edge)
    //   regC  : max(E*4, N*F*2) bytes — es (bucket->agg), then Pb (node->edge)
    float*  xagg = (float*)d_ws;
    ushort* regB = (ushort*)(xagg + (size_t)N * F);
    char*   regC = (char*)regB + (size_t)N * F * 2;
    size_t  regCsz = ((size_t)E * 4 > (size_t)N * F * 2) ? (size_t)E * 4 : (size_t)N * F * 2;
    ushort* xb = regB;
    ushort* Qb = regB;
    int*    es = (int*)regC;
    ushort* Pb = (ushort*)regC;
    int*    deg    = (int*)(regC + regCsz);
    float*  dinv   = (float*)(deg + N);
    float*  M      = dinv + N;
    int*    rowptr = (int*)(M + 8320);
    int*    fill   = rowptr + N;
    int*    bsum   = fill + N;
    int*    boffs  = bsum + 512;

    hipMemsetAsync(deg, 0, (size_t)N * sizeof(int), stream);
    hipMemsetAsync(fill, 0, (size_t)N * sizeof(int), stream);

    k_deg<<<(E + 255) / 256, 256, 0, stream>>>(dst, deg, E);
    k_dinv<<<NB, 256, 0, stream>>>(deg, dinv, N);
    k_weights<<<65, 64, 0, stream>>>(Wz, bz, Wh, bh, Wlz, blz, Wlh, blh, M);
    k_xcast<<<(N * F / 4 + 255) / 256, 256, 0, stream>>>(x, xb, N * F / 4);

    // CSR build
    k_blocksum<<<NB, 256, 0, stream>>>(deg, bsum, N);
    k_scanb<<<1, 64, 0, stream>>>(bsum, boffs, NB);
    k_rowptr<<<NB, 256, 0, stream>>>(deg, boffs, rowptr, N);
    k_bucket<<<(E + 255) / 256, 256, 0, stream>>>(src, dst, rowptr, fill, es, E);

    k_agg<<<(N * 64 + 255) / 256, 256, 0, stream>>>(xb, dinv, es, rowptr, deg, xagg, N);

    k_node<<<400, 512, 0, stream>>>(xagg, M, W1, b1, Pb, Qb, N);

    const float* W1c = W1 + 128 * 64;
    k_edge<<<(E + 255) / 256, 256, 0, stream>>>(src, dst, attr, Pb, Qb, W1c, W2, b2, out, E);
}

// Round 4
// 864.784 us; speedup vs baseline: 2.1599x; 2.1599x over previous
//
#include <hip/hip_runtime.h>

#define F 64      // F_IN == HID
#define EF 32
#define COUT 4

typedef unsigned int uint;
typedef unsigned short ushort;

__device__ inline ushort f2bf(float f) {           // RNE float->bf16
    uint u = __float_as_uint(f);
    return (ushort)((u + 0x7fff + ((u >> 16) & 1)) >> 16);
}
__device__ inline float bf2f(ushort u) {
    return __uint_as_float(((uint)u) << 16);
}

// ---------------------------------------------------------------- kernels

__global__ void k_deg(const int* __restrict__ dst, int* __restrict__ deg, int E) {
    int i = blockIdx.x * blockDim.x + threadIdx.x;
    if (i < E) atomicAdd(&deg[dst[i]], 1);
}

__global__ void k_dinv(const int* __restrict__ deg, float* __restrict__ dinv, int n) {
    int i = blockIdx.x * blockDim.x + threadIdx.x;
    if (i < n) dinv[i] = rsqrtf((float)(deg[i] + 1));
}

__global__ void k_xcast(const float* __restrict__ x, ushort* __restrict__ xb, int n4) {
    int i = blockIdx.x * 256 + threadIdx.x;
    if (i >= n4) return;
    float4 v = *(const float4*)(x + (size_t)i * 4);
    ushort4 o;
    o.x = f2bf(v.x); o.y = f2bf(v.y); o.z = f2bf(v.z); o.w = f2bf(v.w);
    *(ushort4*)(xb + (size_t)i * 4) = o;
}

// ---- exclusive scan of deg -> rowptr ----

__global__ void k_blocksum(const int* __restrict__ deg, int* __restrict__ bsum, int n) {
    __shared__ int sm[256];
    int i = blockIdx.x * 256 + threadIdx.x;
    sm[threadIdx.x] = (i < n) ? deg[i] : 0;
    __syncthreads();
    for (int s = 128; s > 0; s >>= 1) {
        if (threadIdx.x < s) sm[threadIdx.x] += sm[threadIdx.x + s];
        __syncthreads();
    }
    if (threadIdx.x == 0) bsum[blockIdx.x] = sm[0];
}

__global__ void k_scanb(const int* __restrict__ bsum, int* __restrict__ boffs, int nb) {
    int lane = threadIdx.x;
    int carry = 0;
    for (int base = 0; base < nb; base += 64) {
        int v = (base + lane < nb) ? bsum[base + lane] : 0;
        int incl = v;
        #pragma unroll
        for (int off = 1; off < 64; off <<= 1) {
            int t = __shfl_up(incl, off);
            if (lane >= off) incl += t;
        }
        if (base + lane < nb) boffs[base + lane] = carry + incl - v;
        carry += __shfl(incl, 63);
    }
}

__global__ void k_rowptr(const int* __restrict__ deg, const int* __restrict__ boffs,
                         int* __restrict__ rowptr, int n) {
    __shared__ int sm[256];
    int tid = threadIdx.x;
    int i = blockIdx.x * 256 + tid;
    int v = (i < n) ? deg[i] : 0;
    sm[tid] = v;
    __syncthreads();
    for (int off = 1; off < 256; off <<= 1) {
        int t = (tid >= off) ? sm[tid - off] : 0;
        __syncthreads();
        sm[tid] += t;
        __syncthreads();
    }
    if (i < n) rowptr[i] = boffs[blockIdx.x] + sm[tid] - v;
}

__global__ void k_bucket(const int* __restrict__ src, const int* __restrict__ dst,
                         const int* __restrict__ rowptr, int* __restrict__ fill,
                         int* __restrict__ es, int E) {
    int e = blockIdx.x * 256 + threadIdx.x;
    if (e >= E) return;
    int d = dst[e];
    int pos = rowptr[d] + atomicAdd(&fill[d], 1);
    es[pos] = src[e];
}

// gather-aggregate: one wave per node, lane = feature (bf16 x rows, f32 accum)
__global__ __launch_bounds__(256) void k_agg(
    const ushort* __restrict__ xb, const float* __restrict__ dinv,
    const int* __restrict__ es, const int* __restrict__ rowptr,
    const int* __restrict__ deg, float* __restrict__ xagg, int n) {
    int node = (blockIdx.x * 256 + threadIdx.x) >> 6;
    int lane = threadIdx.x & 63;
    if (node >= n) return;
    int start = rowptr[node], cnt = deg[node];
    float di = dinv[node];
    float acc = bf2f(xb[(size_t)node * F + lane]) * di * di;
    for (int base = 0; base < cnt; base += 64) {
        int m = min(64, cnt - base);
        int s = 0; float dv = 0.f;
        if (lane < m) { s = es[start + base + lane]; dv = dinv[s]; }
        for (int i = 0; i < m; ++i) {
            int si = __shfl(s, i);
            float wv = __shfl(dv, i) * di;
            acc += bf2f(xb[(size_t)si * F + lane]) * wv;
        }
    }
    xagg[(size_t)node * F + lane] = acc;
}

// M layout: Mz[4096] | Mh[4096] | vz[64] | vh[64]
__global__ void k_weights(const float* __restrict__ Wz, const float* __restrict__ bz,
                          const float* __restrict__ Wh, const float* __restrict__ bh,
                          const float* __restrict__ Wlz, const float* __restrict__ blz,
                          const float* __restrict__ Wlh, const float* __restrict__ blh,
                          float* __restrict__ M) {
    int j = threadIdx.x;
    int k = blockIdx.x;
    if (k < 64) {
        float sz = 0.f, sh = 0.f;
        for (int i = 0; i < 64; ++i) {
            sz += Wz[k * 64 + i] * Wlz[i * 64 + j];
            sh += Wh[k * 64 + i] * Wlh[i * 64 + j];
        }
        M[k * 64 + j]        = sz;
        M[4096 + k * 64 + j] = sh;
    } else {
        float sz = blz[j], sh = blh[j];
        for (int i = 0; i < 64; ++i) {
            sz += bz[i] * Wlz[i * 64 + j];
            sh += bh[i] * Wlh[i * 64 + j];
        }
        M[8192 + j] = sz;
        M[8256 + j] = sh;
    }
}

// Per node: Z=sigmoid(a@Mz+vz); T=tanh(a@Mh+vh); h=(1-Z)T; P=h@W1a+b1; Q=h@W1b (bf16 out)
__global__ __launch_bounds__(512) void k_node(
    const float* __restrict__ xagg, const float* __restrict__ M,
    const float* __restrict__ W1, const float* __restrict__ b1,
    ushort* __restrict__ Pb, ushort* __restrict__ Qb, int n) {
    __shared__ float sm[16384];  // Mz | Mh | W1a | W1b
    for (int i = threadIdx.x; i < 8192; i += 512) sm[i] = M[i];
    for (int i = threadIdx.x; i < 8192; i += 512) sm[8192 + i] = W1[i];
    __syncthreads();
    int wid = threadIdx.x >> 6, lane = threadIdx.x & 63;
    float vz = M[8192 + lane], vh = M[8256 + lane], b1v = b1[lane];
    int wave = blockIdx.x * 8 + wid;
    int nwaves = gridDim.x * 8;
    for (int base = wave * 4; base < n; base += nwaves * 4) {
        float a[4], gz[4], gh[4];
        #pragma unroll
        for (int i = 0; i < 4; ++i) {
            int node = base + i;
            a[i] = (node < n) ? xagg[(size_t)node * F + lane] : 0.f;
            gz[i] = vz; gh[i] = vh;
        }
        #pragma unroll 8
        for (int k = 0; k < 64; ++k) {
            float mz = sm[k * 64 + lane], mh = sm[4096 + k * 64 + lane];
            #pragma unroll
            for (int i = 0; i < 4; ++i) {
                float ak = __shfl(a[i], k);
                gz[i] += ak * mz;
                gh[i] += ak * mh;
            }
        }
        float h[4], p[4], q[4];
        #pragma unroll
        for (int i = 0; i < 4; ++i) {
            float z = 1.f / (1.f + __expf(-gz[i]));
            float t = tanhf(gh[i]);
            h[i] = (1.f - z) * t;
            p[i] = b1v; q[i] = 0.f;
        }
        #pragma unroll 8
        for (int k = 0; k < 64; ++k) {
            float w1a = sm[8192 + k * 64 + lane], w1b = sm[12288 + k * 64 + lane];
            #pragma unroll
            for (int i = 0; i < 4; ++i) {
                float hk = __shfl(h[i], k);
                p[i] += hk * w1a;
                q[i] += hk * w1b;
            }
        }
        #pragma unroll
        for (int i = 0; i < 4; ++i) {
            int node = base + i;
            if (node < n) {
                Pb[(size_t)node * F + lane] = f2bf(p[i]);
                Qb[(size_t)node * F + lane] = f2bf(q[i]);
            }
        }
    }
}

// One edge per LANE; EXACT R1 loop shape (j4 0..15, pre[4], unroll 2),
// only the P/Q loads swapped to bf16 uint2 + unpack.
__global__ __launch_bounds__(256) void k_edge(
    const int* __restrict__ src, const int* __restrict__ dst,
    const float* __restrict__ attr,
    const ushort* __restrict__ Pb, const ushort* __restrict__ Qb,
    const float* __restrict__ W1c, const float* __restrict__ W2,
    const float* __restrict__ b2, float* __restrict__ out, int E) {
    int e = blockIdx.x * 256 + threadIdx.x;
    if (e >= E) return;
    int s = src[e], d = dst[e];
    float ar[EF];
    #pragma unroll
    for (int k4 = 0; k4 < EF / 4; ++k4) {
        float4 v = *(const float4*)(attr + (size_t)e * EF + k4 * 4);
        ar[k4 * 4 + 0] = v.x; ar[k4 * 4 + 1] = v.y;
        ar[k4 * 4 + 2] = v.z; ar[k4 * 4 + 3] = v.w;
    }
    const uint2* Ps = (const uint2*)(Pb + (size_t)s * F);
    const uint2* Qd = (const uint2*)(Qb + (size_t)d * F);
    float o0 = b2[0], o1 = b2[1], o2 = b2[2], o3 = b2[3];
    #pragma unroll 2
    for (int j4 = 0; j4 < 16; ++j4) {
        uint2 pv = Ps[j4];
        uint2 qv = Qd[j4];
        float pre[4];
        pre[0] = __uint_as_float(pv.x << 16)         + __uint_as_float(qv.x << 16);
        pre[1] = __uint_as_float(pv.x & 0xffff0000u) + __uint_as_float(qv.x & 0xffff0000u);
        pre[2] = __uint_as_float(pv.y << 16)         + __uint_as_float(qv.y << 16);
        pre[3] = __uint_as_float(pv.y & 0xffff0000u) + __uint_as_float(qv.y & 0xffff0000u);
        #pragma unroll
        for (int jj = 0; jj < 4; ++jj) {
            int j = j4 * 4 + jj;
            float acc = pre[jj];
            #pragma unroll
            for (int k = 0; k < EF; ++k) acc += ar[k] * W1c[k * 64 + j];
            float h = fmaxf(acc, 0.f);
            o0 += h * W2[j * 4 + 0];
            o1 += h * W2[j * 4 + 1];
            o2 += h * W2[j * 4 + 2];
            o3 += h * W2[j * 4 + 3];
        }
    }
    *(float4*)(out + (size_t)e * 4) = make_float4(o0, o1, o2, o3);
}

// ---------------------------------------------------------------- launch

extern "C" void kernel_launch(void* const* d_in, const int* in_sizes, int n_in,
                              void* d_out, int out_size, void* d_ws, size_t ws_size,
                              hipStream_t stream) {
    const float* x    = (const float*)d_in[0];
    const int*   ei   = (const int*)d_in[1];
    const float* attr = (const float*)d_in[2];
    const float* Wz   = (const float*)d_in[3];
    const float* bz   = (const float*)d_in[4];
    const float* Wh   = (const float*)d_in[7];
    const float* bh   = (const float*)d_in[8];
    const float* Wlz  = (const float*)d_in[9];
    const float* blz  = (const float*)d_in[10];
    const float* Wlh  = (const float*)d_in[13];
    const float* blh  = (const float*)d_in[14];
    const float* W1   = (const float*)d_in[15];
    const float* b1   = (const float*)d_in[16];
    const float* W2   = (const float*)d_in[17];
    const float* b2   = (const float*)d_in[18];
    float* out = (float*)d_out;

    const int N = in_sizes[0] / F;
    const int E = in_sizes[1] / 2;
    const int* src = ei;
    const int* dst = ei + E;
    const int NB = (N + 255) / 256;

    // workspace layout (time-disjoint aliasing):
    //   xagg  : N*F f32                          (k_agg out -> k_node in)
    //   regB  : N*F ushort — xb (xcast->agg), then Qb (node->edge)
    //   regC  : max(E*4, N*F*2) bytes — es (bucket->agg), then Pb (node->edge)
    float*  xagg = (float*)d_ws;
    ushort* regB = (ushort*)(xagg + (size_t)N * F);
    char*   regC = (char*)regB + (size_t)N * F * 2;
    size_t  regCsz = ((size_t)E * 4 > (size_t)N * F * 2) ? (size_t)E * 4 : (size_t)N * F * 2;
    ushort* xb = regB;
    ushort* Qb = regB;
    int*    es = (int*)regC;
    ushort* Pb = (ushort*)regC;
    int*    deg    = (int*)(regC + regCsz);
    float*  dinv   = (float*)(deg + N);
    float*  M      = dinv + N;
    int*    rowptr = (int*)(M + 8320);
    int*    fill   = rowptr + N;
    int*    bsum   = fill + N;
    int*    boffs  = bsum + 512;

    hipMemsetAsync(deg, 0, (size_t)N * sizeof(int), stream);
    hipMemsetAsync(fill, 0, (size_t)N * sizeof(int), stream);

    k_deg<<<(E + 255) / 256, 256, 0, stream>>>(dst, deg, E);
    k_dinv<<<NB, 256, 0, stream>>>(deg, dinv, N);
    k_weights<<<65, 64, 0, stream>>>(Wz, bz, Wh, bh, Wlz, blz, Wlh, blh, M);
    k_xcast<<<(N * F / 4 + 255) / 256, 256, 0, stream>>>(x, xb, N * F / 4);

    // CSR build
    k_blocksum<<<NB, 256, 0, stream>>>(deg, bsum, N);
    k_scanb<<<1, 64, 0, stream>>>(bsum, boffs, NB);
    k_rowptr<<<NB, 256, 0, stream>>>(deg, boffs, rowptr, N);
    k_bucket<<<(E + 255) / 256, 256, 0, stream>>>(src, dst, rowptr, fill, es, E);

    k_agg<<<(N * 64 + 255) / 256, 256, 0, stream>>>(xb, dinv, es, rowptr, deg, xagg, N);

    k_node<<<400, 512, 0, stream>>>(xagg, M, W1, b1, Pb, Qb, N);

    const float* W1c = W1 + 128 * 64;
    k_edge<<<(E + 255) / 256, 256, 0, stream>>>(src, dst, attr, Pb, Qb, W1c, W2, b2, out, E);
}

// Round 5
// 686.674 us; speedup vs baseline: 2.7202x; 1.2594x over previous
//
#include <hip/hip_runtime.h>

#define F 64      // F_IN == HID
#define EF 32
#define COUT 4

typedef unsigned int uint;
typedef unsigned short ushort;

__device__ inline ushort f2bf(float f) {           // RNE float->bf16
    uint u = __float_as_uint(f);
    return (ushort)((u + 0x7fff + ((u >> 16) & 1)) >> 16);
}
__device__ inline float bf2f(ushort u) {
    return __uint_as_float(((uint)u) << 16);
}

// ---------------------------------------------------------------- kernels

__global__ void k_deg(const int* __restrict__ dst, int* __restrict__ deg, int E) {
    int i = blockIdx.x * blockDim.x + threadIdx.x;
    if (i < E) atomicAdd(&deg[dst[i]], 1);
}

__global__ void k_dinv(const int* __restrict__ deg, float* __restrict__ dinv, int n) {
    int i = blockIdx.x * blockDim.x + threadIdx.x;
    if (i < n) dinv[i] = rsqrtf((float)(deg[i] + 1));
}

__global__ void k_xcast(const float* __restrict__ x, ushort* __restrict__ xb, int n4) {
    int i = blockIdx.x * 256 + threadIdx.x;
    if (i >= n4) return;
    float4 v = *(const float4*)(x + (size_t)i * 4);
    ushort4 o;
    o.x = f2bf(v.x); o.y = f2bf(v.y); o.z = f2bf(v.z); o.w = f2bf(v.w);
    *(ushort4*)(xb + (size_t)i * 4) = o;
}

// ---- exclusive scan of deg -> rowptr ----

__global__ void k_blocksum(const int* __restrict__ deg, int* __restrict__ bsum, int n) {
    __shared__ int sm[256];
    int i = blockIdx.x * 256 + threadIdx.x;
    sm[threadIdx.x] = (i < n) ? deg[i] : 0;
    __syncthreads();
    for (int s = 128; s > 0; s >>= 1) {
        if (threadIdx.x < s) sm[threadIdx.x] += sm[threadIdx.x + s];
        __syncthreads();
    }
    if (threadIdx.x == 0) bsum[blockIdx.x] = sm[0];
}

__global__ void k_scanb(const int* __restrict__ bsum, int* __restrict__ boffs, int nb) {
    int lane = threadIdx.x;
    int carry = 0;
    for (int base = 0; base < nb; base += 64) {
        int v = (base + lane < nb) ? bsum[base + lane] : 0;
        int incl = v;
        #pragma unroll
        for (int off = 1; off < 64; off <<= 1) {
            int t = __shfl_up(incl, off);
            if (lane >= off) incl += t;
        }
        if (base + lane < nb) boffs[base + lane] = carry + incl - v;
        carry += __shfl(incl, 63);
    }
}

__global__ void k_rowptr(const int* __restrict__ deg, const int* __restrict__ boffs,
                         int* __restrict__ rowptr, int n) {
    __shared__ int sm[256];
    int tid = threadIdx.x;
    int i = blockIdx.x * 256 + tid;
    int v = (i < n) ? deg[i] : 0;
    sm[tid] = v;
    __syncthreads();
    for (int off = 1; off < 256; off <<= 1) {
        int t = (tid >= off) ? sm[tid - off] : 0;
        __syncthreads();
        sm[tid] += t;
        __syncthreads();
    }
    if (i < n) rowptr[i] = boffs[blockIdx.x] + sm[tid] - v;
}

// bucket entries: (src, edge_id) pairs, grouped by dst
__global__ void k_bucket(const int* __restrict__ src, const int* __restrict__ dst,
                         const int* __restrict__ rowptr, int* __restrict__ fill,
                         int2* __restrict__ es2, int E) {
    int e = blockIdx.x * 256 + threadIdx.x;
    if (e >= E) return;
    int d = dst[e];
    int pos = rowptr[d] + atomicAdd(&fill[d], 1);
    es2[pos] = make_int2(src[e], e);
}

// edst[pos] = owning dst node, for bucket-ordered edge processing
__global__ void k_expand(const int* __restrict__ rowptr, const int* __restrict__ deg,
                         int* __restrict__ edst, int n) {
    int i = blockIdx.x * 256 + threadIdx.x;
    if (i >= n) return;
    int p = rowptr[i], c = deg[i];
    for (int j = 0; j < c; ++j) edst[p + j] = i;
}

// gather-aggregate: one wave per node, lane = feature (bf16 x rows, f32 accum)
__global__ __launch_bounds__(256) void k_agg(
    const ushort* __restrict__ xb, const float* __restrict__ dinv,
    const int2* __restrict__ es2, const int* __restrict__ rowptr,
    const int* __restrict__ deg, float* __restrict__ xagg, int n) {
    int node = (blockIdx.x * 256 + threadIdx.x) >> 6;
    int lane = threadIdx.x & 63;
    if (node >= n) return;
    int start = rowptr[node], cnt = deg[node];
    float di = dinv[node];
    float acc = bf2f(xb[(size_t)node * F + lane]) * di * di;
    for (int base = 0; base < cnt; base += 64) {
        int m = min(64, cnt - base);
        int s = 0; float dv = 0.f;
        if (lane < m) { s = es2[start + base + lane].x; dv = dinv[s]; }
        for (int i = 0; i < m; ++i) {
            int si = __shfl(s, i);
            float wv = __shfl(dv, i) * di;
            acc += bf2f(xb[(size_t)si * F + lane]) * wv;
        }
    }
    xagg[(size_t)node * F + lane] = acc;
}

// M layout: Mz[4096] | Mh[4096] | vz[64] | vh[64]
__global__ void k_weights(const float* __restrict__ Wz, const float* __restrict__ bz,
                          const float* __restrict__ Wh, const float* __restrict__ bh,
                          const float* __restrict__ Wlz, const float* __restrict__ blz,
                          const float* __restrict__ Wlh, const float* __restrict__ blh,
                          float* __restrict__ M) {
    int j = threadIdx.x;
    int k = blockIdx.x;
    if (k < 64) {
        float sz = 0.f, sh = 0.f;
        for (int i = 0; i < 64; ++i) {
            sz += Wz[k * 64 + i] * Wlz[i * 64 + j];
            sh += Wh[k * 64 + i] * Wlh[i * 64 + j];
        }
        M[k * 64 + j]        = sz;
        M[4096 + k * 64 + j] = sh;
    } else {
        float sz = blz[j], sh = blh[j];
        for (int i = 0; i < 64; ++i) {
            sz += bz[i] * Wlz[i * 64 + j];
            sh += bh[i] * Wlh[i * 64 + j];
        }
        M[8192 + j] = sz;
        M[8256 + j] = sh;
    }
}

// Per node: Z=sigmoid(a@Mz+vz); T=tanh(a@Mh+vh); h=(1-Z)T; P=h@W1a+b1; Q=h@W1b (bf16 out)
__global__ __launch_bounds__(512) void k_node(
    const float* __restrict__ xagg, const float* __restrict__ M,
    const float* __restrict__ W1, const float* __restrict__ b1,
    ushort* __restrict__ Pb, ushort* __restrict__ Qb, int n) {
    __shared__ float sm[16384];  // Mz | Mh | W1a | W1b
    for (int i = threadIdx.x; i < 8192; i += 512) sm[i] = M[i];
    for (int i = threadIdx.x; i < 8192; i += 512) sm[8192 + i] = W1[i];
    __syncthreads();
    int wid = threadIdx.x >> 6, lane = threadIdx.x & 63;
    float vz = M[8192 + lane], vh = M[8256 + lane], b1v = b1[lane];
    int wave = blockIdx.x * 8 + wid;
    int nwaves = gridDim.x * 8;
    for (int base = wave * 4; base < n; base += nwaves * 4) {
        float a[4], gz[4], gh[4];
        #pragma unroll
        for (int i = 0; i < 4; ++i) {
            int node = base + i;
            a[i] = (node < n) ? xagg[(size_t)node * F + lane] : 0.f;
            gz[i] = vz; gh[i] = vh;
        }
        #pragma unroll 8
        for (int k = 0; k < 64; ++k) {
            float mz = sm[k * 64 + lane], mh = sm[4096 + k * 64 + lane];
            #pragma unroll
            for (int i = 0; i < 4; ++i) {
                float ak = __shfl(a[i], k);
                gz[i] += ak * mz;
                gh[i] += ak * mh;
            }
        }
        float h[4], p[4], q[4];
        #pragma unroll
        for (int i = 0; i < 4; ++i) {
            float z = 1.f / (1.f + __expf(-gz[i]));
            float t = tanhf(gh[i]);
            h[i] = (1.f - z) * t;
            p[i] = b1v; q[i] = 0.f;
        }
        #pragma unroll 8
        for (int k = 0; k < 64; ++k) {
            float w1a = sm[8192 + k * 64 + lane], w1b = sm[12288 + k * 64 + lane];
            #pragma unroll
            for (int i = 0; i < 4; ++i) {
                float hk = __shfl(h[i], k);
                p[i] += hk * w1a;
                q[i] += hk * w1b;
            }
        }
        #pragma unroll
        for (int i = 0; i < 4; ++i) {
            int node = base + i;
            if (node < n) {
                Pb[(size_t)node * F + lane] = f2bf(p[i]);
                Qb[(size_t)node * F + lane] = f2bf(q[i]);
            }
        }
    }
}

// Bucket-ordered edge MLP: consecutive lanes share dst -> Q[d] rows L1-broadcast.
// Inner loop = exact R3 shape (proven codegen).
__global__ __launch_bounds__(256) void k_edge(
    const int2* __restrict__ es2, const int* __restrict__ edst,
    const float* __restrict__ attr,
    const ushort* __restrict__ Pb, const ushort* __restrict__ Qb,
    const float* __restrict__ W1c, const float* __restrict__ W2,
    const float* __restrict__ b2, float* __restrict__ out, int E) {
    int i = blockIdx.x * 256 + threadIdx.x;
    if (i >= E) return;
    int2 se = es2[i];
    int s = se.x, eid = se.y, d = edst[i];
    float ar[EF];
    #pragma unroll
    for (int k4 = 0; k4 < EF / 4; ++k4) {
        float4 v = *(const float4*)(attr + (size_t)eid * EF + k4 * 4);
        ar[k4 * 4 + 0] = v.x; ar[k4 * 4 + 1] = v.y;
        ar[k4 * 4 + 2] = v.z; ar[k4 * 4 + 3] = v.w;
    }
    const uint2* Ps = (const uint2*)(Pb + (size_t)s * F);
    const uint2* Qd = (const uint2*)(Qb + (size_t)d * F);
    float o0 = b2[0], o1 = b2[1], o2 = b2[2], o3 = b2[3];
    #pragma unroll 2
    for (int j4 = 0; j4 < 16; ++j4) {
        uint2 pv = Ps[j4];
        uint2 qv = Qd[j4];
        float pre[4];
        pre[0] = __uint_as_float(pv.x << 16)         + __uint_as_float(qv.x << 16);
        pre[1] = __uint_as_float(pv.x & 0xffff0000u) + __uint_as_float(qv.x & 0xffff0000u);
        pre[2] = __uint_as_float(pv.y << 16)         + __uint_as_float(qv.y << 16);
        pre[3] = __uint_as_float(pv.y & 0xffff0000u) + __uint_as_float(qv.y & 0xffff0000u);
        #pragma unroll
        for (int jj = 0; jj < 4; ++jj) {
            int j = j4 * 4 + jj;
            float acc = pre[jj];
            #pragma unroll
            for (int k = 0; k < EF; ++k) acc += ar[k] * W1c[k * 64 + j];
            float h = fmaxf(acc, 0.f);
            o0 += h * W2[j * 4 + 0];
            o1 += h * W2[j * 4 + 1];
            o2 += h * W2[j * 4 + 2];
            o3 += h * W2[j * 4 + 3];
        }
    }
    *(float4*)(out + (size_t)eid * 4) = make_float4(o0, o1, o2, o3);
}

// ---------------------------------------------------------------- launch

extern "C" void kernel_launch(void* const* d_in, const int* in_sizes, int n_in,
                              void* d_out, int out_size, void* d_ws, size_t ws_size,
                              hipStream_t stream) {
    const float* x    = (const float*)d_in[0];
    const int*   ei   = (const int*)d_in[1];
    const float* attr = (const float*)d_in[2];
    const float* Wz   = (const float*)d_in[3];
    const float* bz   = (const float*)d_in[4];
    const float* Wh   = (const float*)d_in[7];
    const float* bh   = (const float*)d_in[8];
    const float* Wlz  = (const float*)d_in[9];
    const float* blz  = (const float*)d_in[10];
    const float* Wlh  = (const float*)d_in[13];
    const float* blh  = (const float*)d_in[14];
    const float* W1   = (const float*)d_in[15];
    const float* b1   = (const float*)d_in[16];
    const float* W2   = (const float*)d_in[17];
    const float* b2   = (const float*)d_in[18];
    float* out = (float*)d_out;

    const int N = in_sizes[0] / F;
    const int E = in_sizes[1] / 2;
    const int* src = ei;
    const int* dst = ei + E;
    const int NB = (N + 255) / 256;

    // workspace layout (4-byte units); xb dead after k_agg -> Pb aliases it
    float*  xagg = (float*)d_ws;                        // N*F f32
    ushort* regB = (ushort*)(xagg + (size_t)N * F);     // N*F ushort: xb then Pb
    ushort* Qb   = regB + (size_t)N * F;                // N*F ushort
    int2*   es2  = (int2*)(Qb + (size_t)N * F);         // E int2
    int*    edst = (int*)(es2 + (size_t)E);             // E
    int*    deg    = edst + E;                          // N
    float*  dinv   = (float*)(deg + N);                 // N
    float*  M      = dinv + N;                          // 8320
    int*    rowptr = (int*)(M + 8320);                  // N
    int*    fill   = rowptr + N;                        // N
    int*    bsum   = fill + N;                          // <=512
    int*    boffs  = bsum + 512;                        // <=512
    ushort* xb = regB;
    ushort* Pb = regB;

    hipMemsetAsync(deg, 0, (size_t)N * sizeof(int), stream);
    hipMemsetAsync(fill, 0, (size_t)N * sizeof(int), stream);

    k_deg<<<(E + 255) / 256, 256, 0, stream>>>(dst, deg, E);
    k_dinv<<<NB, 256, 0, stream>>>(deg, dinv, N);
    k_weights<<<65, 64, 0, stream>>>(Wz, bz, Wh, bh, Wlz, blz, Wlh, blh, M);
    k_xcast<<<(N * F / 4 + 255) / 256, 256, 0, stream>>>(x, xb, N * F / 4);

    // CSR build
    k_blocksum<<<NB, 256, 0, stream>>>(deg, bsum, N);
    k_scanb<<<1, 64, 0, stream>>>(bsum, boffs, NB);
    k_rowptr<<<NB, 256, 0, stream>>>(deg, boffs, rowptr, N);
    k_bucket<<<(E + 255) / 256, 256, 0, stream>>>(src, dst, rowptr, fill, es2, E);
    k_expand<<<NB, 256, 0, stream>>>(rowptr, deg, edst, N);

    k_agg<<<(N * 64 + 255) / 256, 256, 0, stream>>>(xb, dinv, es2, rowptr, deg, xagg, N);

    k_node<<<400, 512, 0, stream>>>(xagg, M, W1, b1, Pb, Qb, N);

    const float* W1c = W1 + 128 * 64;
    k_edge<<<(E + 255) / 256, 256, 0, stream>>>(es2, edst, attr, Pb, Qb, W1c, W2, b2, out, E);
}

// Round 6
// 500.628 us; speedup vs baseline: 3.7310x; 1.3716x over previous
//
#include <hip/hip_runtime.h>

#define F 64      // F_IN == HID
#define EF 32
#define COUT 4

typedef unsigned int uint;
typedef unsigned short ushort;
typedef __attribute__((ext_vector_type(8))) short bf16x8;
typedef __attribute__((ext_vector_type(4))) float f32x4;

__device__ inline ushort f2bf(float f) {           // RNE float->bf16
    uint u = __float_as_uint(f);
    return (ushort)((u + 0x7fff + ((u >> 16) & 1)) >> 16);
}
__device__ inline float bf2f(ushort u) {
    return __uint_as_float(((uint)u) << 16);
}

// ---------------------------------------------------------------- kernels

__global__ void k_deg(const int* __restrict__ dst, int* __restrict__ deg, int E) {
    int i = blockIdx.x * blockDim.x + threadIdx.x;
    if (i < E) atomicAdd(&deg[dst[i]], 1);
}

__global__ void k_dinv(const int* __restrict__ deg, float* __restrict__ dinv, int n) {
    int i = blockIdx.x * blockDim.x + threadIdx.x;
    if (i < n) dinv[i] = rsqrtf((float)(deg[i] + 1));
}

__global__ void k_xcast(const float* __restrict__ x, ushort* __restrict__ xb, int n4) {
    int i = blockIdx.x * 256 + threadIdx.x;
    if (i >= n4) return;
    float4 v = *(const float4*)(x + (size_t)i * 4);
    ushort4 o;
    o.x = f2bf(v.x); o.y = f2bf(v.y); o.z = f2bf(v.z); o.w = f2bf(v.w);
    *(ushort4*)(xb + (size_t)i * 4) = o;
}

// ---- exclusive scan of deg -> rowptr ----

__global__ void k_blocksum(const int* __restrict__ deg, int* __restrict__ bsum, int n) {
    __shared__ int sm[256];
    int i = blockIdx.x * 256 + threadIdx.x;
    sm[threadIdx.x] = (i < n) ? deg[i] : 0;
    __syncthreads();
    for (int s = 128; s > 0; s >>= 1) {
        if (threadIdx.x < s) sm[threadIdx.x] += sm[threadIdx.x + s];
        __syncthreads();
    }
    if (threadIdx.x == 0) bsum[blockIdx.x] = sm[0];
}

__global__ void k_scanb(const int* __restrict__ bsum, int* __restrict__ boffs, int nb) {
    int lane = threadIdx.x;
    int carry = 0;
    for (int base = 0; base < nb; base += 64) {
        int v = (base + lane < nb) ? bsum[base + lane] : 0;
        int incl = v;
        #pragma unroll
        for (int off = 1; off < 64; off <<= 1) {
            int t = __shfl_up(incl, off);
            if (lane >= off) incl += t;
        }
        if (base + lane < nb) boffs[base + lane] = carry + incl - v;
        carry += __shfl(incl, 63);
    }
}

__global__ void k_rowptr(const int* __restrict__ deg, const int* __restrict__ boffs,
                         int* __restrict__ rowptr, int n) {
    __shared__ int sm[256];
    int tid = threadIdx.x;
    int i = blockIdx.x * 256 + tid;
    int v = (i < n) ? deg[i] : 0;
    sm[tid] = v;
    __syncthreads();
    for (int off = 1; off < 256; off <<= 1) {
        int t = (tid >= off) ? sm[tid - off] : 0;
        __syncthreads();
        sm[tid] += t;
        __syncthreads();
    }
    if (i < n) rowptr[i] = boffs[blockIdx.x] + sm[tid] - v;
}

// bucket entries: (src, edge_id) pairs, grouped by dst
__global__ void k_bucket(const int* __restrict__ src, const int* __restrict__ dst,
                         const int* __restrict__ rowptr, int* __restrict__ fill,
                         int2* __restrict__ es2, int E) {
    int e = blockIdx.x * 256 + threadIdx.x;
    if (e >= E) return;
    int d = dst[e];
    int pos = rowptr[d] + atomicAdd(&fill[d], 1);
    es2[pos] = make_int2(src[e], e);
}

// edst[pos] = owning dst node
__global__ void k_expand(const int* __restrict__ rowptr, const int* __restrict__ deg,
                         int* __restrict__ edst, int n) {
    int i = blockIdx.x * 256 + threadIdx.x;
    if (i >= n) return;
    int p = rowptr[i], c = deg[i];
    for (int j = 0; j < c; ++j) edst[p + j] = i;
}

// gather-aggregate: one wave per node, lane = feature; OUTPUT bf16 now
__global__ __launch_bounds__(256) void k_agg(
    const ushort* __restrict__ xb, const float* __restrict__ dinv,
    const int2* __restrict__ es2, const int* __restrict__ rowptr,
    const int* __restrict__ deg, ushort* __restrict__ xaggb, int n) {
    int node = (blockIdx.x * 256 + threadIdx.x) >> 6;
    int lane = threadIdx.x & 63;
    if (node >= n) return;
    int start = rowptr[node], cnt = deg[node];
    float di = dinv[node];
    float acc = bf2f(xb[(size_t)node * F + lane]) * di * di;
    for (int base = 0; base < cnt; base += 64) {
        int m = min(64, cnt - base);
        int s = 0; float dv = 0.f;
        if (lane < m) { s = es2[start + base + lane].x; dv = dinv[s]; }
        for (int i = 0; i < m; ++i) {
            int si = __shfl(s, i);
            float wv = __shfl(dv, i) * di;
            acc += bf2f(xb[(size_t)si * F + lane]) * wv;
        }
    }
    xaggb[(size_t)node * F + lane] = f2bf(acc);
}

// B1t[c][k] (bf16, col-major over k): c<64 -> Mz[k][c]; c>=64 -> Mh[k][c-64]
// V[0:64]=vz, V[64:128]=vh
__global__ void k_weights(const float* __restrict__ Wz, const float* __restrict__ bz,
                          const float* __restrict__ Wh, const float* __restrict__ bh,
                          const float* __restrict__ Wlz, const float* __restrict__ blz,
                          const float* __restrict__ Wlh, const float* __restrict__ blh,
                          ushort* __restrict__ B1t, float* __restrict__ V) {
    int j = threadIdx.x;   // 0..63
    int k = blockIdx.x;    // 0..64 (64 = biases)
    if (k < 64) {
        float sz = 0.f, sh = 0.f;
        for (int i = 0; i < 64; ++i) {
            sz += Wz[k * 64 + i] * Wlz[i * 64 + j];
            sh += Wh[k * 64 + i] * Wlh[i * 64 + j];
        }
        B1t[j * 64 + k]        = f2bf(sz);
        B1t[(64 + j) * 64 + k] = f2bf(sh);
    } else {
        float sz = blz[j], sh = blh[j];
        for (int i = 0; i < 64; ++i) {
            sz += bz[i] * Wlz[i * 64 + j];
            sh += bh[i] * Wlh[i * 64 + j];
        }
        V[j]      = sz;
        V[64 + j] = sh;
    }
}

// B2t[c][k] (bf16): c<64 -> W1a[k][c]=W1[k][c]; c>=64 -> W1b[k][c-64]=W1[64+k][c-64]
__global__ void k_wcast(const float* __restrict__ W1, ushort* __restrict__ B2t) {
    int i = blockIdx.x * 256 + threadIdx.x;
    if (i >= 8192) return;
    int c = i >> 6, k = i & 63;
    int row = (c < 64) ? k : (64 + k);
    B2t[i] = f2bf(W1[row * 64 + (c & 63)]);
}

// MFMA node kernel: one block per 64-node tile; 4 waves.
// GEMM1: [64x64] @ [64x128] -> gates -> h ; GEMM2: h @ [64x128] -> P|Q.
// Lane maps (16x16x32): A row=l&15,k=(l>>4)*8+j ; B col=l&15,same k ; D col=l&15,row=(l>>4)*4+r.
__global__ __launch_bounds__(256) void k_node(
    const ushort* __restrict__ xaggb, const ushort* __restrict__ B1t,
    const ushort* __restrict__ B2t, const float* __restrict__ V,
    const float* __restrict__ b1,
    ushort* __restrict__ Pb, ushort* __restrict__ Qb, int n) {
    __shared__ ushort hsm[64 * 64];  // 8 KiB, XOR-swizzled
    int wid = threadIdx.x >> 6, lane = threadIdx.x & 63;
    int lg = lane >> 4, lc = lane & 15;
    int base = blockIdx.x * 64;

    // preload B fragments (weights fixed for whole kernel)
    bf16x8 b1f[2][2], b2f[2][2];
    #pragma unroll
    for (int t = 0; t < 2; ++t) {
        int c1 = ((t ? wid + 4 : wid) * 16 + lc) * 64;   // GEMM1: Z tile wid, T tile wid+4
        int c2 = ((wid * 2 + t) * 16 + lc) * 64;         // GEMM2: tiles 2*wid, 2*wid+1
        #pragma unroll
        for (int ks = 0; ks < 2; ++ks) {
            b1f[t][ks] = *(const bf16x8*)(B1t + c1 + ks * 32 + lg * 8);
            b2f[t][ks] = *(const bf16x8*)(B2t + c2 + ks * 32 + lg * 8);
        }
    }
    float vzc = V[wid * 16 + lc], vhc = V[64 + wid * 16 + lc];
    float bP[2];
    #pragma unroll
    for (int t = 0; t < 2; ++t) {
        int c2 = (wid * 2 + t) * 16 + lc;
        bP[t] = (c2 < 64) ? b1[c2] : 0.f;
    }

    const f32x4 fz = {0.f, 0.f, 0.f, 0.f};
    f32x4 accZ[4], accT[4];
    #pragma unroll
    for (int rt = 0; rt < 4; ++rt) { accZ[rt] = fz; accT[rt] = fz; }

    // GEMM1
    #pragma unroll
    for (int rt = 0; rt < 4; ++rt) {
        const ushort* ap = xaggb + (size_t)(base + rt * 16 + lc) * 64 + lg * 8;
        bf16x8 a0 = *(const bf16x8*)(ap);
        bf16x8 a1 = *(const bf16x8*)(ap + 32);
        accZ[rt] = __builtin_amdgcn_mfma_f32_16x16x32_bf16(a0, b1f[0][0], accZ[rt], 0, 0, 0);
        accZ[rt] = __builtin_amdgcn_mfma_f32_16x16x32_bf16(a1, b1f[0][1], accZ[rt], 0, 0, 0);
        accT[rt] = __builtin_amdgcn_mfma_f32_16x16x32_bf16(a0, b1f[1][0], accT[rt], 0, 0, 0);
        accT[rt] = __builtin_amdgcn_mfma_f32_16x16x32_bf16(a1, b1f[1][1], accT[rt], 0, 0, 0);
    }

    // gates -> h -> LDS (swizzled)
    #pragma unroll
    for (int rt = 0; rt < 4; ++rt) {
        #pragma unroll
        for (int r = 0; r < 4; ++r) {
            float z = 1.f / (1.f + __expf(-(accZ[rt][r] + vzc)));
            float tt = tanhf(accT[rt][r] + vhc);
            float h = (1.f - z) * tt;
            int row = rt * 16 + lg * 4 + r;
            int byte = ((row * 64 + wid * 16 + lc) * 2) ^ ((row & 7) << 4);
            *(ushort*)((char*)hsm + byte) = f2bf(h);
        }
    }
    __syncthreads();

    // GEMM2
    f32x4 acc2[2][4];
    #pragma unroll
    for (int rt = 0; rt < 4; ++rt) { acc2[0][rt] = fz; acc2[1][rt] = fz; }
    #pragma unroll
    for (int rt = 0; rt < 4; ++rt) {
        #pragma unroll
        for (int ks = 0; ks < 2; ++ks) {
            int row = rt * 16 + lc;
            int byte = (row * 128 + ks * 64 + lg * 16) ^ ((row & 7) << 4);
            bf16x8 a2 = *(const bf16x8*)((char*)hsm + byte);
            acc2[0][rt] = __builtin_amdgcn_mfma_f32_16x16x32_bf16(a2, b2f[0][ks], acc2[0][rt], 0, 0, 0);
            acc2[1][rt] = __builtin_amdgcn_mfma_f32_16x16x32_bf16(a2, b2f[1][ks], acc2[1][rt], 0, 0, 0);
        }
    }

    // store P (waves 0,1) / Q (waves 2,3)
    ushort* dstb = (wid < 2) ? Pb : Qb;
    #pragma unroll
    for (int t = 0; t < 2; ++t) {
        int cl = ((wid * 2 + t) * 16 + lc) & 63;
        #pragma unroll
        for (int rt = 0; rt < 4; ++rt) {
            #pragma unroll
            for (int r = 0; r < 4; ++r) {
                int node = base + rt * 16 + lg * 4 + r;
                if (node < n) dstb[(size_t)node * 64 + cl] = f2bf(acc2[t][rt][r] + bP[t]);
            }
        }
    }
}

// Bucket-ordered edge MLP (unchanged from R4)
__global__ __launch_bounds__(256) void k_edge(
    const int2* __restrict__ es2, const int* __restrict__ edst,
    const float* __restrict__ attr,
    const ushort* __restrict__ Pb, const ushort* __restrict__ Qb,
    const float* __restrict__ W1c, const float* __restrict__ W2,
    const float* __restrict__ b2, float* __restrict__ out, int E) {
    int i = blockIdx.x * 256 + threadIdx.x;
    if (i >= E) return;
    int2 se = es2[i];
    int s = se.x, eid = se.y, d = edst[i];
    float ar[EF];
    #pragma unroll
    for (int k4 = 0; k4 < EF / 4; ++k4) {
        float4 v = *(const float4*)(attr + (size_t)eid * EF + k4 * 4);
        ar[k4 * 4 + 0] = v.x; ar[k4 * 4 + 1] = v.y;
        ar[k4 * 4 + 2] = v.z; ar[k4 * 4 + 3] = v.w;
    }
    const uint2* Ps = (const uint2*)(Pb + (size_t)s * F);
    const uint2* Qd = (const uint2*)(Qb + (size_t)d * F);
    float o0 = b2[0], o1 = b2[1], o2 = b2[2], o3 = b2[3];
    #pragma unroll 2
    for (int j4 = 0; j4 < 16; ++j4) {
        uint2 pv = Ps[j4];
        uint2 qv = Qd[j4];
        float pre[4];
        pre[0] = __uint_as_float(pv.x << 16)         + __uint_as_float(qv.x << 16);
        pre[1] = __uint_as_float(pv.x & 0xffff0000u) + __uint_as_float(qv.x & 0xffff0000u);
        pre[2] = __uint_as_float(pv.y << 16)         + __uint_as_float(qv.y << 16);
        pre[3] = __uint_as_float(pv.y & 0xffff0000u) + __uint_as_float(qv.y & 0xffff0000u);
        #pragma unroll
        for (int jj = 0; jj < 4; ++jj) {
            int j = j4 * 4 + jj;
            float acc = pre[jj];
            #pragma unroll
            for (int k = 0; k < EF; ++k) acc += ar[k] * W1c[k * 64 + j];
            float h = fmaxf(acc, 0.f);
            o0 += h * W2[j * 4 + 0];
            o1 += h * W2[j * 4 + 1];
            o2 += h * W2[j * 4 + 2];
            o3 += h * W2[j * 4 + 3];
        }
    }
    *(float4*)(out + (size_t)eid * 4) = make_float4(o0, o1, o2, o3);
}

// ---------------------------------------------------------------- launch

extern "C" void kernel_launch(void* const* d_in, const int* in_sizes, int n_in,
                              void* d_out, int out_size, void* d_ws, size_t ws_size,
                              hipStream_t stream) {
    const float* x    = (const float*)d_in[0];
    const int*   ei   = (const int*)d_in[1];
    const float* attr = (const float*)d_in[2];
    const float* Wz   = (const float*)d_in[3];
    const float* bz   = (const float*)d_in[4];
    const float* Wh   = (const float*)d_in[7];
    const float* bh   = (const float*)d_in[8];
    const float* Wlz  = (const float*)d_in[9];
    const float* blz  = (const float*)d_in[10];
    const float* Wlh  = (const float*)d_in[13];
    const float* blh  = (const float*)d_in[14];
    const float* W1   = (const float*)d_in[15];
    const float* b1   = (const float*)d_in[16];
    const float* W2   = (const float*)d_in[17];
    const float* b2   = (const float*)d_in[18];
    float* out = (float*)d_out;

    const int N = in_sizes[0] / F;
    const int E = in_sizes[1] / 2;
    const int* src = ei;
    const int* dst = ei + E;
    const int NB = (N + 255) / 256;
    const int NBT = (N + 63) / 64;

    // workspace layout; xb dead after k_agg -> Pb aliases it
    ushort* xaggb = (ushort*)d_ws;                      // N*F ushort
    ushort* regB  = xaggb + (size_t)N * F;              // N*F ushort: xb then Pb
    ushort* Qb    = regB + (size_t)N * F;               // N*F ushort
    ushort* B1t   = Qb + (size_t)N * F;                 // 8192
    ushort* B2t   = B1t + 8192;                         // 8192
    float*  V     = (float*)(B2t + 8192);               // 128
    int2*   es2   = (int2*)(V + 128);                   // E int2
    int*    edst  = (int*)(es2 + (size_t)E);            // E
    int*    deg   = edst + E;                           // N
    float*  dinv  = (float*)(deg + N);                  // N
    int*    rowptr= (int*)(dinv + N);                   // N
    int*    fill  = rowptr + N;                         // N
    int*    bsum  = fill + N;                           // <=512
    int*    boffs = bsum + 512;                         // <=512
    ushort* xb = regB;
    ushort* Pb = regB;

    hipMemsetAsync(deg, 0, (size_t)N * sizeof(int), stream);
    hipMemsetAsync(fill, 0, (size_t)N * sizeof(int), stream);

    k_deg<<<(E + 255) / 256, 256, 0, stream>>>(dst, deg, E);
    k_dinv<<<NB, 256, 0, stream>>>(deg, dinv, N);
    k_weights<<<65, 64, 0, stream>>>(Wz, bz, Wh, bh, Wlz, blz, Wlh, blh, B1t, V);
    k_wcast<<<32, 256, 0, stream>>>(W1, B2t);
    k_xcast<<<(N * F / 4 + 255) / 256, 256, 0, stream>>>(x, xb, N * F / 4);

    // CSR build
    k_blocksum<<<NB, 256, 0, stream>>>(deg, bsum, N);
    k_scanb<<<1, 64, 0, stream>>>(bsum, boffs, NB);
    k_rowptr<<<NB, 256, 0, stream>>>(deg, boffs, rowptr, N);
    k_bucket<<<(E + 255) / 256, 256, 0, stream>>>(src, dst, rowptr, fill, es2, E);
    k_expand<<<NB, 256, 0, stream>>>(rowptr, deg, edst, N);

    k_agg<<<(N * 64 + 255) / 256, 256, 0, stream>>>(xb, dinv, es2, rowptr, deg, xaggb, N);

    k_node<<<NBT, 256, 0, stream>>>(xaggb, B1t, B2t, V, b1, Pb, Qb, N);

    const float* W1c = W1 + 128 * 64;
    k_edge<<<(E + 255) / 256, 256, 0, stream>>>(es2, edst, attr, Pb, Qb, W1c, W2, b2, out, E);
}